// Round 10
// baseline (309.964 us; speedup 1.0000x reference)
//
#include <hip/hip_runtime.h>

#define BATCH   16384
#define NV      128
#define NH      256
#define NSTEP   64
#define WD      4160
#define NCHUNK_TOT 156   // sum over steps of ceil(i/16)

typedef __attribute__((ext_vector_type(8))) short bf16x8;
typedef __attribute__((ext_vector_type(4))) float f32x4;
typedef __attribute__((ext_vector_type(2))) float f32x2;
typedef __attribute__((ext_vector_type(4))) unsigned int u32x4;

__device__ __forceinline__ unsigned int cvtpk(float lo, float hi) {
    unsigned int d;
    asm("v_cvt_pk_bf16_f32 %0, %1, %2" : "=v"(d) : "v"(lo), "v"(hi));
    return d;   // [lo_bf16 | hi_bf16 << 16], RNE
}
__device__ __forceinline__ int nchunk_of(int i) { return (i + 15) >> 4; }
__device__ __forceinline__ int chunk_off(int i) {   // # of 32-wide K chunks in steps < i
    if (i <= 1) return 0;
    int q = (i - 1) >> 4;
    return 8 * q * (q + 1) + (i - 1 - 16 * q) * (q + 1);
}

// Fused pack: blocks [0,1024) pack x-fragments (one n-tile each, wave per chunk);
// blocks [1024,1280) pack w-fragments (one (step,chunk) each; chunk 0 also writes
// Cstep = exp(-0.5*sum b_c^2) and deinterleaved cur-pair weights B0/B1).
__global__ __launch_bounds__(256) void pack_xw(const float* __restrict__ x,
                                               const float* __restrict__ w,
                                               unsigned short* __restrict__ xfrag,
                                               unsigned short* __restrict__ wfrag,
                                               float* __restrict__ Cstep,
                                               float* __restrict__ B0pk,
                                               float* __restrict__ B1pk) {
    const int bid = blockIdx.x;
    const int t = threadIdx.x;
    if (bid < 1024) {
        const int nt = bid, c = t >> 6;
        const int l = t & 63, lm = l & 15, lk = l >> 4;
        const float* xrow = x + (size_t)(nt * 16 + lm) * NV + c * 32 + lk * 8;
        float4 v0 = *(const float4*)(xrow);
        float4 v1 = *(const float4*)(xrow + 4);
        u32x4 pk = { cvtpk(v0.x, v0.y), cvtpk(v0.z, v0.w),
                     cvtpk(v1.x, v1.y), cvtpk(v1.z, v1.w) };
        *(u32x4*)(xfrag + ((size_t)(nt * 4 + c) * 64 + l) * 8) = pk;
    } else {
        const int idx2 = bid - 1024;
        const int i = idx2 >> 2, q = idx2 & 3, m = t;
        const int K = 2 * i, s = i * i + i;
        const int nc = nchunk_of(i), base = chunk_off(i);
        const int tc = m >> 4, lm = m & 15;
        const float* wrow = w + (size_t)m * WD + s;
        if (q < nc) {
            const int c = q;
            size_t fb = ((size_t)(base + c) * 16 + tc) * 512;
            #pragma unroll
            for (int lk = 0; lk < 4; lk++) {
                const float* wp = wrow + c * 32 + lk * 8;
                float4 v0 = *(const float4*)(wp);
                float4 v1 = *(const float4*)(wp + 4);
                const int k0 = c * 32 + lk * 8;
                // K even -> each (even,odd) pair is fully in- or out-of-range
                u32x4 pk;
                pk[0] = (k0 + 0 < K) ? cvtpk(v0.x, v0.y) : 0u;
                pk[1] = (k0 + 2 < K) ? cvtpk(v0.z, v0.w) : 0u;
                pk[2] = (k0 + 4 < K) ? cvtpk(v1.x, v1.y) : 0u;
                pk[3] = (k0 + 6 < K) ? cvtpk(v1.z, v1.w) : 0u;
                *(u32x4*)(wfrag + fb + ((size_t)lk * 16 + lm) * 8) = pk;
            }
        }
        if (q == 0) {
            float b0 = wrow[K], b1 = wrow[K + 1], b01 = b0 + b1;
            B0pk[i * NH + m] = b0;
            B1pk[i * NH + m] = b1;
            float s0 = b0 * b0, s1 = b1 * b1, s2 = b01 * b01;
            #pragma unroll
            for (int off = 1; off < 64; off <<= 1) {
                s0 += __shfl_xor(s0, off);
                s1 += __shfl_xor(s1, off);
                s2 += __shfl_xor(s2, off);
            }
            __shared__ float red[3][4];
            if ((m & 63) == 0) { red[0][m >> 6] = s0; red[1][m >> 6] = s1; red[2][m >> 6] = s2; }
            __syncthreads();
            if (m < 3) {
                float tot = red[m][0] + red[m][1] + red[m][2] + red[m][3];
                Cstep[i * 3 + m] = expf(-0.5f * tot);
            }
        }
    }
}

// psi = ratio_idx / sqrt(sum_c ratio_c^2), ratio_c = C_c*exp(-T_c),
// T_c = sum_m b_c[m]*tan(av[n,m]); P0 = prod cos cancels (never computed).
// Each wave owns 16 n x all 256 m: m-reduce completes in-wave
// (in-lane f32x4 + horiz + xor16/xor32) -> zero LDS, zero barriers.
__global__ __launch_bounds__(256) void psi_kernel(
    const unsigned short* __restrict__ xfrag,
    const unsigned short* __restrict__ wfrag,
    const float* __restrict__ x,
    const float* __restrict__ hb, const float* __restrict__ Cstep,
    const float* __restrict__ B0pk, const float* __restrict__ B1pk,
    float* __restrict__ psi)
{
    const int i  = blockIdx.y;           // step
    const int nb = blockIdx.x;           // 64-row batch tile
    const int t = threadIdx.x, wv = t >> 6, l = t & 63;
    const int lm = l & 15, lk = l >> 4;
    const int K = 2 * i;
    const int nc = nchunk_of(i), base = chunk_off(i);

    // acc init = bias (D row = m = mt*16 + lk*4 + r, col = n = lane&15)
    f32x4 acc[16];
    #pragma unroll
    for (int mt = 0; mt < 16; mt++)
        acc[mt] = *(const f32x4*)(hb + mt * 16 + lk * 4);

    // this wave's A-fragment stream (n-tile nb*4 + wv), all 16 W-tiles per chunk
    const unsigned short* xptr = xfrag + ((size_t)(nb * 4 + wv) * 4) * 512 + (size_t)l * 8;
    const unsigned short* wptr = wfrag + (size_t)base * 16 * 512 + (size_t)l * 8;

    for (int c = 0; c < nc; c++) {
        bf16x8 fa = *(const bf16x8*)(xptr + (size_t)c * 512);
        #pragma unroll
        for (int mt = 0; mt < 16; mt++) {
            bf16x8 fb = *(const bf16x8*)(wptr + ((size_t)c * 16 + mt) * 512);
            acc[mt] = __builtin_amdgcn_mfma_f32_16x16x32_bf16(fb, fa, acc[mt], 0, 0, 0);
        }
    }

    // epilogue: T_c = sum_m b_c[m]*tan(av), tan(av) ~ av*(1+av^2/3)
    const float* B0 = B0pk + i * NH + lk * 4;
    const float* B1 = B1pk + i * NH + lk * 4;
    f32x4 T0v = {0.f, 0.f, 0.f, 0.f}, T1v = {0.f, 0.f, 0.f, 0.f};
    #pragma unroll
    for (int mt = 0; mt < 16; mt++) {
        f32x4 b0 = *(const f32x4*)(B0 + mt * 16);
        f32x4 b1 = *(const f32x4*)(B1 + mt * 16);
        #pragma unroll
        for (int r = 0; r < 4; r++) {
            float av = acc[mt][r];
            float tt = av * av;
            float ta = av * fmaf(tt, 0.333333333f, 1.0f);
            T0v[r] = fmaf(b0[r], ta, T0v[r]);
            T1v[r] = fmaf(b1[r], ta, T1v[r]);
        }
    }
    float T0 = (T0v[0] + T0v[1]) + (T0v[2] + T0v[3]);
    float T1 = (T1v[0] + T1v[1]) + (T1v[2] + T1v[3]);
    T0 += __shfl_xor(T0, 16);  T0 += __shfl_xor(T0, 32);
    T1 += __shfl_xor(T1, 16);  T1 += __shfl_xor(T1, 32);

    if (lk == 0) {
        const int n = nb * 64 + wv * 16 + lm;
        float C1 = Cstep[i * 3 + 0], C2 = Cstep[i * 3 + 1], C3 = Cstep[i * 3 + 2];
        float T3 = T0 + T1;
        float e1 = fmaf(T0, fmaf(T0, 0.5f, -1.0f), 1.0f);   // exp(-T) ~ 1 - T + T^2/2
        float e2 = fmaf(T1, fmaf(T1, 0.5f, -1.0f), 1.0f);
        float e3 = fmaf(T3, fmaf(T3, 0.5f, -1.0f), 1.0f);
        float r1 = e1 * C1, r2 = e2 * C2, r3 = e3 * C3;
        float norm = fmaxf(sqrtf(fmaf(r1, r1, fmaf(r2, r2, fmaf(r3, r3, 1.0f)))), 1e-14f);
        f32x2 vc = *(const f32x2*)(x + (size_t)n * NV + K);
        int idx = (int)(vc[0] + 2.0f * vc[1]);
        float pc = (idx == 0) ? 1.0f : (idx == 1) ? r1 : (idx == 2) ? r2 : r3;
        psi[(size_t)i * BATCH + n] = pc / norm;
    }
}

__global__ __launch_bounds__(256) void prod_kernel(
    const float* __restrict__ psi, float* __restrict__ out)
{
    int n = blockIdx.x * blockDim.x + threadIdx.x;
    if (n < BATCH) {
        float pr = 1.0f;
        #pragma unroll
        for (int i = 0; i < NSTEP; i++) pr *= psi[(size_t)i * BATCH + n];
        out[n] = pr;
    }
}

extern "C" void kernel_launch(void* const* d_in, const int* in_sizes, int n_in,
                              void* d_out, int out_size, void* d_ws, size_t ws_size,
                              hipStream_t stream) {
    const float* x  = (const float*)d_in[0];
    const float* w  = (const float*)d_in[1];
    const float* hb = (const float*)d_in[2];
    float* out = (float*)d_out;

    // workspace: psi 4MB | xfrag 4MB | wfrag 2.56MB | Cstep 192f | B0 16K f | B1 16K f
    float* psi = (float*)d_ws;
    unsigned short* xfrag = (unsigned short*)((char*)d_ws + (size_t)NSTEP * BATCH * 4);
    unsigned short* wfrag = xfrag + (size_t)1024 * 4 * 512;
    float* Cstep = (float*)(wfrag + (size_t)NCHUNK_TOT * 16 * 512);
    float* B0pk  = Cstep + 192;
    float* B1pk  = B0pk + NSTEP * NH;

    pack_xw<<<1280, 256, 0, stream>>>(x, w, xfrag, wfrag, Cstep, B0pk, B1pk);
    dim3 grid(BATCH / 64, NSTEP);
    psi_kernel<<<grid, 256, 0, stream>>>(xfrag, wfrag, x, hb, Cstep, B0pk, B1pk, psi);
    prod_kernel<<<(BATCH + 255) / 256, 256, 0, stream>>>(psi, out);
}

// Round 11
// 114.525 us; speedup vs baseline: 2.7065x; 2.7065x over previous
//
#include <hip/hip_runtime.h>

#define BATCH   16384
#define NV      128
#define NH      256
#define NSTEP   64
#define WD      4160

typedef __attribute__((ext_vector_type(8))) short bf16x8;
typedef __attribute__((ext_vector_type(4))) float f32x4;
typedef __attribute__((ext_vector_type(4))) unsigned int u32x4;

__device__ __forceinline__ unsigned short f2bf(float f) {
    unsigned int u = __float_as_uint(f);
    return (unsigned short)((u + 0x7FFFu + ((u >> 16) & 1u)) >> 16);
}
__device__ __forceinline__ unsigned int cvtpk(float lo, float hi) {
    unsigned int d;
    asm("v_cvt_pk_bf16_f32 %0, %1, %2" : "=v"(d) : "v"(lo), "v"(hi));
    return d;
}

// prep: one block per step i. Builds, exactly in fp32:
//   tb_c[m] = tan(b_c[m]),  d_c = sum_m tb_c*hb[m],  G_c = exp(sum_m log cos b_c)
//   u_c[i,k] = sum_m tb_c[m]*W[m, s_i+k]  (k < 2i, else 0)
// and writes u as bf16 MFMA A-fragments (column j = c*64+i of a 192x128 matrix).
__global__ __launch_bounds__(256) void prep_kernel(const float* __restrict__ w,
                                                   const float* __restrict__ hb,
                                                   unsigned short* __restrict__ ufrag,
                                                   float* __restrict__ gd) {
    const int i = blockIdx.x, t = threadIdx.x;
    const int K = 2 * i, s = i * i + i;
    const int wv = t >> 6, lane = t & 63;

    __shared__ float tb_s[3][NH];
    __shared__ float part[2][3][128];
    __shared__ float u_l[3][128];
    __shared__ float red[6][4];
    __shared__ float tot[6];

    {   // per-m constants + 6 block reductions (3 d_c, 3 -log G_c)
        const int m = t;
        float b0 = w[(size_t)m * WD + s + K];
        float b1 = w[(size_t)m * WD + s + K + 1];
        float b2 = b0 + b1;
        float tb0 = b0 * fmaf(b0 * b0, 0.333333333f, 1.0f);   // tan b ~ b(1+b^2/3)
        float tb1 = b1 * fmaf(b1 * b1, 0.333333333f, 1.0f);
        float tb2 = b2 * fmaf(b2 * b2, 0.333333333f, 1.0f);
        tb_s[0][m] = tb0; tb_s[1][m] = tb1; tb_s[2][m] = tb2;
        float hbm = hb[m];
        float q0 = b0 * b0, q1 = b1 * b1, q2 = b2 * b2;
        float v[6];
        v[0] = tb0 * hbm; v[1] = tb1 * hbm; v[2] = tb2 * hbm;
        v[3] = fmaf(q0, q0 * (1.0f / 12.0f), 0.5f * q0);      // -log cos b ~ b^2/2 + b^4/12
        v[4] = fmaf(q1, q1 * (1.0f / 12.0f), 0.5f * q1);
        v[5] = fmaf(q2, q2 * (1.0f / 12.0f), 0.5f * q2);
        #pragma unroll
        for (int j = 0; j < 6; j++) {
            float xx = v[j];
            #pragma unroll
            for (int off = 1; off < 64; off <<= 1) xx += __shfl_xor(xx, off);
            if (lane == 0) red[j][wv] = xx;
        }
    }
    for (int o = t; o < 384; o += 256) u_l[o >> 7][o & 127] = 0.0f;
    __syncthreads();
    if (t < 6) tot[t] = red[t][0] + red[t][1] + red[t][2] + red[t][3];

    // u dot-phase: wave (khalf, mhalf): lanes = consecutive k (coalesced W reads),
    // serial m with LDS-broadcast tb.
    const int khalf = wv & 1, mhalf = wv >> 1;
    const int k = khalf * 64 + lane;
    float a0 = 0.f, a1 = 0.f, a2 = 0.f;
    if (k < K) {
        const float* wp = w + s + k;
        const int m0 = mhalf * 128;
        for (int m = m0; m < m0 + 128; m++) {
            float wval = wp[(size_t)m * WD];
            a0 = fmaf(tb_s[0][m], wval, a0);
            a1 = fmaf(tb_s[1][m], wval, a1);
            a2 = fmaf(tb_s[2][m], wval, a2);
        }
    }
    part[mhalf][0][k] = a0; part[mhalf][1][k] = a1; part[mhalf][2][k] = a2;
    __syncthreads();
    for (int o = t; o < 384; o += 256) {
        int c = o >> 7, kk = o & 127;
        if (kk < K) u_l[c][kk] = part[0][c][kk] + part[1][c][kk];
    }
    __syncthreads();

    if (t < 48) {   // write this step's 3 columns as A-fragments (128 bf16 each)
        const int c = t >> 4, p = t & 15, ch = p >> 2, lkk = p & 3;
        bf16x8 vv;
        #pragma unroll
        for (int e = 0; e < 8; e++) vv[e] = (short)f2bf(u_l[c][ch * 32 + lkk * 8 + e]);
        const int mt = c * 4 + (i >> 4);
        const int dst = lkk * 16 + (i & 15);
        *(bf16x8*)(ufrag + ((size_t)(mt * 4 + ch) * 64 + dst) * 8) = vv;
    }
    if (t < 3) {
        float2 g = make_float2(tot[t], expf(-tot[3 + t]));
        ((float2*)gd)[i * 3 + t] = g;
    }
}

// packx: x -> bf16 B-fragments + packed 2-bit idx codes (16B per n).
__global__ __launch_bounds__(256) void packx_kernel(const float* __restrict__ x,
                                                    unsigned short* __restrict__ xfrag,
                                                    unsigned char* __restrict__ idxcode) {
    const int nt = blockIdx.x, t = threadIdx.x;
    const int c = t >> 6, l = t & 63, lm = l & 15, lk = l >> 4;
    const float* xrow = x + (size_t)(nt * 16 + lm) * NV + c * 32 + lk * 8;
    float4 v0 = *(const float4*)(xrow);
    float4 v1 = *(const float4*)(xrow + 4);
    u32x4 pk = { cvtpk(v0.x, v0.y), cvtpk(v0.z, v0.w),
                 cvtpk(v1.x, v1.y), cvtpk(v1.z, v1.w) };
    *(u32x4*)(xfrag + ((size_t)(nt * 4 + c) * 64 + l) * 8) = pk;
    int i0 = (int)(v0.x + 2.0f * v0.y), i1 = (int)(v0.z + 2.0f * v0.w);
    int i2 = (int)(v1.x + 2.0f * v1.y), i3 = (int)(v1.z + 2.0f * v1.w);
    idxcode[(size_t)(nt * 16 + lm) * 16 + c * 4 + lk] =
        (unsigned char)(i0 | (i1 << 2) | (i2 << 4) | (i3 << 6));
}

// out: T = x . U (one 16x192 MFMA tile-row per wave, K=128), then per-(n,i)
// factor = r_sel/sqrt(1+r1^2+r2^2+r3^2), r_c = G_c*exp(-(d_c + u.x)); product
// over the lane's 16 i, cross-lane product over lk -> out[n]. No psi array.
__global__ __launch_bounds__(256) void out_kernel(const unsigned short* __restrict__ xfrag,
                                                  const unsigned short* __restrict__ ufrag,
                                                  const float* __restrict__ gd,
                                                  const unsigned char* __restrict__ idxcode,
                                                  float* __restrict__ out) {
    const int t = threadIdx.x, wv = t >> 6, l = t & 63;
    const int lm = l & 15, lk = l >> 4;
    const int nt = blockIdx.x * 4 + wv;

    f32x4 acc[12];
    #pragma unroll
    for (int mt = 0; mt < 12; mt++) acc[mt] = (f32x4){0.f, 0.f, 0.f, 0.f};

    const unsigned short* xb = xfrag + (size_t)nt * 4 * 512 + (size_t)l * 8;
    const unsigned short* ub = ufrag + (size_t)l * 8;
    #pragma unroll
    for (int ch = 0; ch < 4; ch++) {
        bf16x8 fa = *(const bf16x8*)(xb + ch * 512);
        #pragma unroll
        for (int mt = 0; mt < 12; mt++) {
            bf16x8 fb = *(const bf16x8*)(ub + (size_t)(mt * 4 + ch) * 512);
            acc[mt] = __builtin_amdgcn_mfma_f32_16x16x32_bf16(fb, fa, acc[mt], 0, 0, 0);
        }
    }

    const int n = nt * 16 + lm;
    u32x4 idxw = *(const u32x4*)(idxcode + (size_t)n * 16);
    const float2* gdp = (const float2*)gd;
    float prodp = 1.0f;
    #pragma unroll
    for (int mtl = 0; mtl < 4; mtl++) {
        #pragma unroll
        for (int r = 0; r < 4; r++) {
            const int i = mtl * 16 + lk * 4 + r;
            float2 g1 = gdp[i * 3 + 0], g2 = gdp[i * 3 + 1], g3 = gdp[i * 3 + 2];
            float T1 = acc[mtl][r]     + g1.x;
            float T2 = acc[4 + mtl][r] + g2.x;
            float T3 = acc[8 + mtl][r] + g3.x;
            float r1 = g1.y * fmaf(T1, fmaf(T1, 0.5f, -1.0f), 1.0f);  // G*exp(-T)
            float r2 = g2.y * fmaf(T2, fmaf(T2, 0.5f, -1.0f), 1.0f);
            float r3 = g3.y * fmaf(T3, fmaf(T3, 0.5f, -1.0f), 1.0f);
            float norm2 = fmaf(r1, r1, fmaf(r2, r2, fmaf(r3, r3, 1.0f)));
            float rn = rsqrtf(norm2);
            rn = rn * fmaf(-0.5f * norm2, rn * rn, 1.5f);             // NR refine
            unsigned idx = (idxw[mtl] >> ((lk * 4 + r) * 2)) & 3u;
            float pc = (idx == 0) ? 1.0f : (idx == 1) ? r1 : (idx == 2) ? r2 : r3;
            prodp *= pc * rn;
        }
    }
    prodp *= __shfl_xor(prodp, 16);
    prodp *= __shfl_xor(prodp, 32);
    if (lk == 0) out[n] = prodp;
}

extern "C" void kernel_launch(void* const* d_in, const int* in_sizes, int n_in,
                              void* d_out, int out_size, void* d_ws, size_t ws_size,
                              hipStream_t stream) {
    const float* x  = (const float*)d_in[0];
    const float* w  = (const float*)d_in[1];
    const float* hb = (const float*)d_in[2];
    float* out = (float*)d_out;

    // ws: xfrag 4MB | ufrag 48KB | gd 1.5KB(pad 2KB) | idxcode 256KB
    unsigned short* xfrag = (unsigned short*)d_ws;
    unsigned short* ufrag = xfrag + (size_t)1024 * 4 * 512;
    float* gd = (float*)((char*)ufrag + 49152);
    unsigned char* idxcode = (unsigned char*)gd + 2048;

    packx_kernel<<<1024, 256, 0, stream>>>(x, xfrag, idxcode);
    prep_kernel<<<64, 256, 0, stream>>>(w, hb, ufrag, gd);
    out_kernel<<<256, 256, 0, stream>>>(xfrag, ufrag, gd, idxcode, out);
}

// Round 14
// 75.867 us; speedup vs baseline: 4.0856x; 1.5095x over previous
//
#include <hip/hip_runtime.h>

#define BATCH   16384
#define NV      128
#define NH      256
#define NSTEP   64
#define WD      4160

typedef __attribute__((ext_vector_type(8))) short bf16x8;
typedef __attribute__((ext_vector_type(4))) float f32x4;
typedef __attribute__((ext_vector_type(4))) unsigned int u32x4;

__device__ __forceinline__ unsigned short f2bf(float f) {
    unsigned int u = __float_as_uint(f);
    return (unsigned short)((u + 0x7FFFu + ((u >> 16) & 1u)) >> 16);
}
__device__ __forceinline__ unsigned int cvtpk(float lo, float hi) {
    unsigned int d;
    asm("v_cvt_pk_bf16_f32 %0, %1, %2" : "=v"(d) : "v"(lo), "v"(hi));
    return d;
}

// Fused pack+prep, one launch.
// blocks [0,256):  pack x -> bf16 B-fragments + 2-bit idx codes (4 n-tiles/block)
// blocks [256,320): per-step prep (i = bid-256):
//   tb_c[m]=tan(b_c), d_c=sum tb_c*hb, G_c=exp(sum log cos b_c)
//   u_c[k]=sum_m tb_c[m]*W[m,s+k]  (k<2i else 0) -> bf16 A-fragments.
// 16 waves: m split 8-ways x k split 2-ways; 32-load chain fully unrolled
// (32 outstanding loads/thread -> one latency exposure, not 128).
__global__ __launch_bounds__(1024) void pack_prep(
    const float* __restrict__ x, const float* __restrict__ w,
    const float* __restrict__ hb,
    unsigned short* __restrict__ xfrag, unsigned char* __restrict__ idxcode,
    unsigned short* __restrict__ ufrag, float* __restrict__ gd)
{
    const int bid = blockIdx.x, t = threadIdx.x;
    if (bid < 256) {
        const int nt = bid * 4 + (t >> 8);
        const int c = (t >> 6) & 3, l = t & 63, lm = l & 15, lk = l >> 4;
        const float* xrow = x + (size_t)(nt * 16 + lm) * NV + c * 32 + lk * 8;
        float4 v0 = *(const float4*)(xrow);
        float4 v1 = *(const float4*)(xrow + 4);
        u32x4 pk = { cvtpk(v0.x, v0.y), cvtpk(v0.z, v0.w),
                     cvtpk(v1.x, v1.y), cvtpk(v1.z, v1.w) };
        *(u32x4*)(xfrag + ((size_t)(nt * 4 + c) * 64 + l) * 8) = pk;
        int i0 = (int)(v0.x + 2.0f * v0.y), i1 = (int)(v0.z + 2.0f * v0.w);
        int i2 = (int)(v1.x + 2.0f * v1.y), i3 = (int)(v1.z + 2.0f * v1.w);
        idxcode[(size_t)(nt * 16 + lm) * 16 + c * 4 + lk] =
            (unsigned char)(i0 | (i1 << 2) | (i2 << 4) | (i3 << 6));
        return;
    }

    const int i = bid - 256;
    const int K = 2 * i, s = i * i + i;
    const int wv = t >> 6, lane = t & 63;

    __shared__ float tb_s[3][NH];
    __shared__ float part[8][3][128];
    __shared__ float u_l[3][128];
    __shared__ float red[6][4];
    __shared__ float tot[6];

    if (t < 256) {   // per-m constants + 6 block reductions (3 d_c, 3 -log G_c)
        const int m = t;
        float b0 = w[(size_t)m * WD + s + K];
        float b1 = w[(size_t)m * WD + s + K + 1];
        float b2 = b0 + b1;
        float tb0 = b0 * fmaf(b0 * b0, 0.333333333f, 1.0f);   // tan b ~ b(1+b^2/3)
        float tb1 = b1 * fmaf(b1 * b1, 0.333333333f, 1.0f);
        float tb2 = b2 * fmaf(b2 * b2, 0.333333333f, 1.0f);
        tb_s[0][m] = tb0; tb_s[1][m] = tb1; tb_s[2][m] = tb2;
        float hbm = hb[m];
        float q0 = b0 * b0, q1 = b1 * b1, q2 = b2 * b2;
        float v[6];
        v[0] = tb0 * hbm; v[1] = tb1 * hbm; v[2] = tb2 * hbm;
        v[3] = fmaf(q0, q0 * (1.0f / 12.0f), 0.5f * q0);      // -log cos b ~ b^2/2 + b^4/12
        v[4] = fmaf(q1, q1 * (1.0f / 12.0f), 0.5f * q1);
        v[5] = fmaf(q2, q2 * (1.0f / 12.0f), 0.5f * q2);
        #pragma unroll
        for (int j = 0; j < 6; j++) {
            float xx = v[j];
            #pragma unroll
            for (int off = 1; off < 64; off <<= 1) xx += __shfl_xor(xx, off);
            if (lane == 0) red[j][wv] = xx;
        }
    }
    for (int o = t; o < 384; o += 1024) u_l[o >> 7][o & 127] = 0.0f;
    __syncthreads();
    if (t < 6) tot[t] = red[t][0] + red[t][1] + red[t][2] + red[t][3];

    // u dot-phase: wave -> (khalf = wv&1, mgrp = wv>>1); lanes = consecutive k.
    const int khalf = wv & 1, mgrp = wv >> 1;
    const int k = khalf * 64 + lane;
    float a0 = 0.f, a1 = 0.f, a2 = 0.f;
    if (k < K) {
        const float* wp = w + (size_t)(mgrp * 32) * WD + s + k;
        float wv32[32];
        #pragma unroll
        for (int j = 0; j < 32; j++) wv32[j] = wp[(size_t)j * WD];   // 32 loads in flight
        #pragma unroll
        for (int j = 0; j < 32; j++) {
            const int m = mgrp * 32 + j;
            a0 = fmaf(tb_s[0][m], wv32[j], a0);
            a1 = fmaf(tb_s[1][m], wv32[j], a1);
            a2 = fmaf(tb_s[2][m], wv32[j], a2);
        }
    }
    part[mgrp][0][k] = a0; part[mgrp][1][k] = a1; part[mgrp][2][k] = a2;
    __syncthreads();
    for (int o = t; o < 384; o += 1024) {
        const int c = o >> 7, kk = o & 127;
        if (kk < K) {
            float sum = 0.f;
            #pragma unroll
            for (int g = 0; g < 8; g++) sum += part[g][c][kk];
            u_l[c][kk] = sum;
        }
    }
    __syncthreads();

    if (t < 48) {   // write this step's 3 columns as A-fragments (128 bf16 each)
        const int c = t >> 4, p = t & 15, ch = p >> 2, lkk = p & 3;
        bf16x8 vv;
        #pragma unroll
        for (int e = 0; e < 8; e++) vv[e] = (short)f2bf(u_l[c][ch * 32 + lkk * 8 + e]);
        const int mt = c * 4 + (i >> 4);
        const int dst = lkk * 16 + (i & 15);
        *(bf16x8*)(ufrag + ((size_t)(mt * 4 + ch) * 64 + dst) * 8) = vv;
    }
    if (t < 3) {
        float2 g = make_float2(tot[t], expf(-tot[3 + t]));
        ((float2*)gd)[i * 3 + t] = g;
    }
}

// out: T = x . U (one 16x192 MFMA tile-row per wave, K=128), then per-(n,i)
// factor = r_sel/sqrt(1+r1^2+r2^2+r3^2), r_c = G_c*exp(-(d_c + u.x)); product
// over the lane's 16 i, cross-lane product over lk -> out[n]. No psi array.
__global__ __launch_bounds__(256) void out_kernel(const unsigned short* __restrict__ xfrag,
                                                  const unsigned short* __restrict__ ufrag,
                                                  const float* __restrict__ gd,
                                                  const unsigned char* __restrict__ idxcode,
                                                  float* __restrict__ out) {
    const int t = threadIdx.x, wv = t >> 6, l = t & 63;
    const int lm = l & 15, lk = l >> 4;
    const int nt = blockIdx.x * 4 + wv;

    f32x4 acc[12];
    #pragma unroll
    for (int mt = 0; mt < 12; mt++) acc[mt] = (f32x4){0.f, 0.f, 0.f, 0.f};

    const unsigned short* xb = xfrag + (size_t)nt * 4 * 512 + (size_t)l * 8;
    const unsigned short* ub = ufrag + (size_t)l * 8;
    #pragma unroll
    for (int ch = 0; ch < 4; ch++) {
        bf16x8 fa = *(const bf16x8*)(xb + ch * 512);
        #pragma unroll
        for (int mt = 0; mt < 12; mt++) {
            bf16x8 fb = *(const bf16x8*)(ub + (size_t)(mt * 4 + ch) * 512);
            acc[mt] = __builtin_amdgcn_mfma_f32_16x16x32_bf16(fb, fa, acc[mt], 0, 0, 0);
        }
    }

    const int n = nt * 16 + lm;
    u32x4 idxw = *(const u32x4*)(idxcode + (size_t)n * 16);
    const float2* gdp = (const float2*)gd;
    float prodp = 1.0f;
    #pragma unroll
    for (int mtl = 0; mtl < 4; mtl++) {
        #pragma unroll
        for (int r = 0; r < 4; r++) {
            const int i = mtl * 16 + lk * 4 + r;
            float2 g1 = gdp[i * 3 + 0], g2 = gdp[i * 3 + 1], g3 = gdp[i * 3 + 2];
            float T1 = acc[mtl][r]     + g1.x;
            float T2 = acc[4 + mtl][r] + g2.x;
            float T3 = acc[8 + mtl][r] + g3.x;
            float r1 = g1.y * fmaf(T1, fmaf(T1, 0.5f, -1.0f), 1.0f);  // G*exp(-T)
            float r2 = g2.y * fmaf(T2, fmaf(T2, 0.5f, -1.0f), 1.0f);
            float r3 = g3.y * fmaf(T3, fmaf(T3, 0.5f, -1.0f), 1.0f);
            float norm2 = fmaf(r1, r1, fmaf(r2, r2, fmaf(r3, r3, 1.0f)));
            float rn = rsqrtf(norm2);
            rn = rn * fmaf(-0.5f * norm2, rn * rn, 1.5f);             // NR refine
            unsigned idx = (idxw[mtl] >> ((lk * 4 + r) * 2)) & 3u;
            float pc = (idx == 0) ? 1.0f : (idx == 1) ? r1 : (idx == 2) ? r2 : r3;
            prodp *= pc * rn;
        }
    }
    prodp *= __shfl_xor(prodp, 16);
    prodp *= __shfl_xor(prodp, 32);
    if (lk == 0) out[n] = prodp;
}

extern "C" void kernel_launch(void* const* d_in, const int* in_sizes, int n_in,
                              void* d_out, int out_size, void* d_ws, size_t ws_size,
                              hipStream_t stream) {
    const float* x  = (const float*)d_in[0];
    const float* w  = (const float*)d_in[1];
    const float* hb = (const float*)d_in[2];
    float* out = (float*)d_out;

    // ws: xfrag 4MB | ufrag 48KB | gd 1.5KB(pad 2KB) | idxcode 256KB
    unsigned short* xfrag = (unsigned short*)d_ws;
    unsigned short* ufrag = xfrag + (size_t)1024 * 4 * 512;
    float* gd = (float*)((char*)ufrag + 49152);
    unsigned char* idxcode = (unsigned char*)gd + 2048;

    pack_prep<<<320, 1024, 0, stream>>>(x, w, hb, xfrag, idxcode, ufrag, gd);
    out_kernel<<<256, 256, 0, stream>>>(xfrag, ufrag, gd, idxcode, out);
}